// Round 2
// baseline (578.782 us; speedup 1.0000x reference)
//
#include <hip/hip_runtime.h>
#include <hip/hip_bf16.h>

#define O_DIM 8192
#define I_DIM 8192
#define G_DIM 64
#define RANK  128

typedef __bf16 bf16x8 __attribute__((ext_vector_type(8)));
typedef __bf16 bf16x4 __attribute__((ext_vector_type(4)));
typedef float  f32x4  __attribute__((ext_vector_type(4)));

// ---- pre-pass 1: svd_up [8192 x 128] f32 -> bf16, same layout ----
__global__ void k_convert_up(const float* __restrict__ up, __bf16* __restrict__ A_bf) {
    size_t t = (size_t)blockIdx.x * blockDim.x + threadIdx.x;   // 262144 threads, 4 elems each
    const float4* in4 = (const float4*)up;
    float4 v = in4[t];
    bf16x4 o = { (__bf16)v.x, (__bf16)v.y, (__bf16)v.z, (__bf16)v.w };
    *(bf16x4*)(A_bf + 4 * t) = o;
}

// ---- pre-pass 2: svd_down [128 x 8192] f32 -> Bt [8192 x 128] bf16 (transposed) ----
__global__ void k_transpose_down(const float* __restrict__ down, __bf16* __restrict__ Bt) {
    __shared__ __bf16 tile[64][132];        // +4 pad keeps 8B alignment, breaks bank stride
    int tid = threadIdx.x;
    int ib  = blockIdx.x * 64;              // i-range of this block
    int il  = tid & 63;
    int k4  = tid >> 6;
    for (int kk = 0; kk < 32; ++kk) {
        int k = kk * 4 + k4;
        tile[il][k] = (__bf16)down[(size_t)k * I_DIM + ib + il];   // coalesced 256B reads
    }
    __syncthreads();
    // output region is contiguous: Bt[ib*128 .. (ib+64)*128)
    uint2* dst = (uint2*)(Bt + (size_t)ib * RANK);
    #pragma unroll
    for (int jj = 0; jj < 8; ++jj) {
        int f   = (jj * 256 + tid) * 4;     // element index, multiple of 4
        int i_l = f >> 7;
        int k_l = f & 127;
        dst[jj * 256 + tid] = *(const uint2*)&tile[i_l][k_l];      // coalesced 8B writes
    }
}

// ---- main fused kernel: one block = 128x128 output tile, 4 independent waves ----
// Barrier-free design: each wave DMAs ITS OWN 64x64 weight quadrant into its own
// 16 KB LDS region and reads back only that region, so the block barrier is
// replaced by a per-wave s_waitcnt vmcnt(0) (vmcnt is per-wave state). Issue
// order matters (vmcnt is FIFO): 32 fragment loads FIRST, then the 16 weight
// DMAs, then MFMA -> the MFMA gate is vmcnt(16) and the ~900 cy weight latency
// hides under MFMA + other waves' work instead of being drained before it.
__global__ __launch_bounds__(256, 2)
void k_main(const int* __restrict__ weight, const float* __restrict__ scale,
            const float* __restrict__ zp, const __bf16* __restrict__ A_bf,
            const __bf16* __restrict__ Bt_bf, float* __restrict__ out) {
    __shared__ int w_lds[4 * 64 * 64];      // 64 KB: per-wave private [64][64] quadrants
    int tid = threadIdx.x;
    int g       = blockIdx.x;               // column group == scale group (tile width 128 == GS)
    int rowbase = blockIdx.y * 128;
    int colbase = g * 128;

    int w    = tid >> 6;
    int lane = tid & 63;
    int l15  = lane & 15;
    int quad = lane >> 4;
    int wrow = (w >> 1) * 64;               // wave's 64x64 quadrant of the 128x128 tile
    int wcol = (w & 1) * 64;

    // ---- (1) fragment loads FIRST: all 32 x 16B, so their vmcnt wait doesn't
    //      require the weight DMAs (issued after) to drain.
    // A-frag: A[m=lane&15][k=quad*8+j]  (m89/m120 measured layout)
    const __bf16* Ap = A_bf  + (size_t)(rowbase + wrow + l15) * RANK + quad * 8;
    const __bf16* Bp = Bt_bf + (size_t)(colbase + wcol + l15) * RANK + quad * 8;
    bf16x8 af[4][4], bfr[4][4];             // [kc][rb/cb]
    #pragma unroll
    for (int kc = 0; kc < 4; ++kc) {
        #pragma unroll
        for (int rb = 0; rb < 4; ++rb) {
            af[kc][rb]  = *(const bf16x8*)(Ap + rb * 16 * RANK + kc * 32);
            bfr[kc][rb] = *(const bf16x8*)(Bp + rb * 16 * RANK + kc * 32);
        }
    }

    // ---- (2) async weight-quadrant DMA: 16 x 1KB global_load_lds dwordx4 ----
    // instr jj fills local rows [jj*4, jj*4+4) of this wave's [64][64] region;
    // lane l supplies global addr for its 16B slot: row jj*4+(l>>4), col (l&15)*4.
    {
        int* ldst = &w_lds[w * 4096];
        const int* gsrc = weight + (size_t)(rowbase + wrow + (lane >> 4)) * I_DIM
                        + colbase + wcol + ((lane & 15) * 4);
        #pragma unroll
        for (int jj = 0; jj < 16; ++jj) {
            __builtin_amdgcn_global_load_lds(
                (const __attribute__((address_space(1))) void*)(gsrc + (size_t)(jj * 4) * I_DIM),
                (__attribute__((address_space(3))) void*)(ldst + jj * 256),
                16, 0, 0);
        }
    }

    // ---- (3) scale/zp into registers (used only after the final drain) ----
    int orow0 = wrow + quad * 4;            // local row base; + rb*16 + r
    float sv[16], zv[16];
    #pragma unroll
    for (int i = 0; i < 16; ++i) {
        int row = rowbase + orow0 + (i >> 2) * 16 + (i & 3);
        sv[i] = scale[(size_t)row * G_DIM + g];
        zv[i] = zp[(size_t)row * G_DIM + g];
    }

    // ---- (4) MFMA: gated on fragments only (vmcnt(16): DMAs stay in flight) ----
    f32x4 acc[4][4];
    #pragma unroll
    for (int rb = 0; rb < 4; ++rb)
        #pragma unroll
        for (int cb = 0; cb < 4; ++cb)
            acc[rb][cb] = (f32x4){0.f, 0.f, 0.f, 0.f};

    #pragma unroll
    for (int kc = 0; kc < 4; ++kc)
        #pragma unroll
        for (int rb = 0; rb < 4; ++rb)
            #pragma unroll
            for (int cb = 0; cb < 4; ++cb)
                acc[rb][cb] = __builtin_amdgcn_mfma_f32_16x16x32_bf16(
                    af[kc][rb], bfr[kc][cb], acc[kc ? rb : rb][cb], 0, 0, 0);

    // ---- (5) per-wave drain: NO __syncthreads (no phase-lock across waves) ----
    asm volatile("s_waitcnt vmcnt(0)" ::: "memory");
    __builtin_amdgcn_sched_barrier(0);      // rule 18: pin following ops behind the wait

    // ---- (6) epilogue: dequant from own LDS quadrant + correction, stream out.
    // cbx = cb ^ (quad&1): per-quad column permutation -> 2 quads per 16-bank
    // half = 2-way LDS access (free, m136) instead of 4-way. Stores stay 64B
    // row-segments (4 rows x 64B per wave-instr), same full write merging.
    const int* wq = &w_lds[w * 4096];
    size_t base = (size_t)(rowbase + orow0) * I_DIM + colbase + wcol + l15;
    #pragma unroll
    for (int rb = 0; rb < 4; ++rb) {
        #pragma unroll
        for (int r = 0; r < 4; ++r) {
            float s = sv[rb * 4 + r];
            float z = zv[rb * 4 + r];
            int row_local = quad * 4 + rb * 16 + r;
            #pragma unroll
            for (int cb = 0; cb < 4; ++cb) {
                int cbx = cb ^ (quad & 1);
                float v = fmaf((float)wq[row_local * 64 + l15 + cbx * 16], s, z)
                        + acc[rb][cbx][r];
                out[base + (size_t)(rb * 16 + r) * I_DIM + cbx * 16] = v;
            }
        }
    }
}

extern "C" void kernel_launch(void* const* d_in, const int* in_sizes, int n_in,
                              void* d_out, int out_size, void* d_ws, size_t ws_size,
                              hipStream_t stream) {
    const int*   weight = (const int*)d_in[0];
    const float* scale  = (const float*)d_in[1];
    const float* zp     = (const float*)d_in[2];
    const float* up     = (const float*)d_in[3];
    const float* down   = (const float*)d_in[4];
    float* out = (float*)d_out;

    __bf16* A_bf  = (__bf16*)d_ws;                  // 8192*128 bf16 = 2 MB
    __bf16* Bt_bf = A_bf + (size_t)O_DIM * RANK;    // 8192*128 bf16 = 2 MB

    k_convert_up<<<1024, 256, 0, stream>>>(up, A_bf);
    k_transpose_down<<<128, 256, 0, stream>>>(down, Bt_bf);

    dim3 grid(64, 64);   // x = column group (g), y = row tile
    k_main<<<grid, 256, 0, stream>>>(weight, scale, zp, A_bf, Bt_bf, out);
}

// Round 3
// 465.966 us; speedup vs baseline: 1.2421x; 1.2421x over previous
//
#include <hip/hip_runtime.h>
#include <hip/hip_bf16.h>

#define O_DIM 8192
#define I_DIM 8192
#define G_DIM 64
#define RANK  128

typedef __bf16 bf16x8 __attribute__((ext_vector_type(8)));
typedef __bf16 bf16x4 __attribute__((ext_vector_type(4)));
typedef float  f32x4  __attribute__((ext_vector_type(4)));

// ---- pre-pass 1: svd_up [8192 x 128] f32 -> bf16, same layout ----
__global__ void k_convert_up(const float* __restrict__ up, __bf16* __restrict__ A_bf) {
    size_t t = (size_t)blockIdx.x * blockDim.x + threadIdx.x;   // 262144 threads, 4 elems each
    const float4* in4 = (const float4*)up;
    float4 v = in4[t];
    bf16x4 o = { (__bf16)v.x, (__bf16)v.y, (__bf16)v.z, (__bf16)v.w };
    *(bf16x4*)(A_bf + 4 * t) = o;
}

// ---- pre-pass 2: svd_down [128 x 8192] f32 -> Bt [8192 x 128] bf16 (transposed) ----
__global__ void k_transpose_down(const float* __restrict__ down, __bf16* __restrict__ Bt) {
    __shared__ __bf16 tile[64][132];        // +4 pad keeps 8B alignment, breaks bank stride
    int tid = threadIdx.x;
    int ib  = blockIdx.x * 64;              // i-range of this block
    int il  = tid & 63;
    int k4  = tid >> 6;
    for (int kk = 0; kk < 32; ++kk) {
        int k = kk * 4 + k4;
        tile[il][k] = (__bf16)down[(size_t)k * I_DIM + ib + il];   // coalesced 256B reads
    }
    __syncthreads();
    // output region is contiguous: Bt[ib*128 .. (ib+64)*128)
    uint2* dst = (uint2*)(Bt + (size_t)ib * RANK);
    #pragma unroll
    for (int jj = 0; jj < 8; ++jj) {
        int f   = (jj * 256 + tid) * 4;     // element index, multiple of 4
        int i_l = f >> 7;
        int k_l = f & 127;
        dst[jj * 256 + tid] = *(const uint2*)&tile[i_l][k_l];      // coalesced 8B writes
    }
}

// ---- main fused kernel: one block = 128x128 output tile, 4 independent waves ----
// Barrier-free: each wave DMAs ITS OWN 64x64 weight quadrant into a private 16 KB
// LDS region and reads back only that region -> block barrier replaced by a
// per-wave s_waitcnt vmcnt(0). vmcnt is FIFO, so issue order is enforced with
// sched_barrier(0) fences: [32 frag loads][scale/zp][16 weight DMAs][MFMA].
// The DMAs are the LAST VMEM before MFMA, so the MFMA gate waits only on the
// fragments while 16 KB/wave of weight stays in flight (8 waves/CU -> 128 KB
// posted per CU, far past the ~9 KB Little's-law floor for 6.3 TB/s).
// NOTE (round-2 lesson, rule #20): every acc[][] index below is compile-time;
// runtime-indexing acc spilled 256 B/thread to scratch and doubled WRITE_SIZE.
__global__ __launch_bounds__(256, 2)
void k_main(const int* __restrict__ weight, const float* __restrict__ scale,
            const float* __restrict__ zp, const __bf16* __restrict__ A_bf,
            const __bf16* __restrict__ Bt_bf, float* __restrict__ out) {
    __shared__ int w_lds[4 * 64 * 64];      // 64 KB: per-wave private [64][64] quadrants
    int tid = threadIdx.x;
    int g       = blockIdx.x;               // column group == scale group (tile width 128 == GS)
    int rowbase = blockIdx.y * 128;
    int colbase = g * 128;

    int w    = tid >> 6;
    int lane = tid & 63;
    int l15  = lane & 15;
    int quad = lane >> 4;
    int wrow = (w >> 1) * 64;               // wave's 64x64 quadrant of the 128x128 tile
    int wcol = (w & 1) * 64;
    int orow0 = wrow + quad * 4;            // local row base; + rb*16 + r

    // ---- (1) fragment loads FIRST (oldest in the vmcnt FIFO) ----
    // A-frag: A[m=lane&15][k=quad*8+j]  (m89/m120 measured layout)
    const __bf16* Ap = A_bf  + (size_t)(rowbase + wrow + l15) * RANK + quad * 8;
    const __bf16* Bp = Bt_bf + (size_t)(colbase + wcol + l15) * RANK + quad * 8;
    bf16x8 af[4][4], bfr[4][4];             // [kc][rb/cb]
    #pragma unroll
    for (int kc = 0; kc < 4; ++kc) {
        #pragma unroll
        for (int rb = 0; rb < 4; ++rb) {
            af[kc][rb]  = *(const bf16x8*)(Ap + rb * 16 * RANK + kc * 32);
            bfr[kc][rb] = *(const bf16x8*)(Bp + rb * 16 * RANK + kc * 32);
        }
    }
    __builtin_amdgcn_sched_barrier(0);      // frags strictly before scale/zp & DMAs

    // ---- (2) scale/zp into registers (consumed only after the final drain) ----
    // 16 lanes (l15) share each address -> 4 unique addrs per wave-instr; L2-hot.
    float sv[16], zv[16];
    #pragma unroll
    for (int i = 0; i < 16; ++i) {
        int row = rowbase + orow0 + (i >> 2) * 16 + (i & 3);
        sv[i] = scale[(size_t)row * G_DIM + g];
        zv[i] = zp[(size_t)row * G_DIM + g];
    }
    __builtin_amdgcn_sched_barrier(0);      // scale/zp strictly before DMAs

    // ---- (3) async weight-quadrant DMA: 16 x 1KB global_load_lds dwordx4 ----
    // instr jj fills local rows [jj*4, jj*4+4): lane l -> row jj*4+(l>>4),
    // col (l&15)*4; LDS dest is wave-uniform base + lane*16 (linear, rule 21).
    {
        int* ldst = &w_lds[w * 4096];
        const int* gsrc = weight + (size_t)(rowbase + wrow + (lane >> 4)) * I_DIM
                        + colbase + wcol + ((lane & 15) * 4);
        #pragma unroll
        for (int jj = 0; jj < 16; ++jj) {
            __builtin_amdgcn_global_load_lds(
                (const __attribute__((address_space(1))) void*)(gsrc + (size_t)(jj * 4) * I_DIM),
                (__attribute__((address_space(3))) void*)(ldst + jj * 256),
                16, 0, 0);
        }
    }
    __builtin_amdgcn_sched_barrier(0);      // DMAs issued before any MFMA-side waits

    // ---- (4) MFMA: gate is vmcnt(16) -> fragments done, DMAs stay in flight ----
    f32x4 acc[4][4];
    #pragma unroll
    for (int rb = 0; rb < 4; ++rb)
        #pragma unroll
        for (int cb = 0; cb < 4; ++cb)
            acc[rb][cb] = (f32x4){0.f, 0.f, 0.f, 0.f};

    #pragma unroll
    for (int kc = 0; kc < 4; ++kc)
        #pragma unroll
        for (int rb = 0; rb < 4; ++rb)
            #pragma unroll
            for (int cb = 0; cb < 4; ++cb)
                acc[rb][cb] = __builtin_amdgcn_mfma_f32_16x16x32_bf16(
                    af[kc][rb], bfr[kc][cb], acc[rb][cb], 0, 0, 0);

    // ---- (5) per-wave drain: NO __syncthreads (no phase-lock across waves) ----
    asm volatile("s_waitcnt vmcnt(0)" ::: "memory");
    __builtin_amdgcn_sched_barrier(0);      // rule 18: pin epilogue behind the wait

    // ---- (6) epilogue: dequant from own LDS quadrant + correction, stream out.
    // ds_read_b32 4-way bank conflict here costs ~2K cy/SIMD total (~1 us,
    // measured r1: 2.1M conflict-cycles chip-wide) - accepted, NOT worth any
    // runtime-indexed acc permutation (r2: that spilled acc, +100 us).
    const int* wq = &w_lds[w * 4096];
    size_t base = (size_t)(rowbase + orow0) * I_DIM + colbase + wcol + l15;
    #pragma unroll
    for (int rb = 0; rb < 4; ++rb) {
        #pragma unroll
        for (int r = 0; r < 4; ++r) {
            float s = sv[rb * 4 + r];
            float z = zv[rb * 4 + r];
            int row_local = quad * 4 + rb * 16 + r;
            #pragma unroll
            for (int cb = 0; cb < 4; ++cb) {
                float v = fmaf((float)wq[row_local * 64 + l15 + cb * 16], s, z)
                        + acc[rb][cb][r];
                out[base + (size_t)(rb * 16 + r) * I_DIM + cb * 16] = v;
            }
        }
    }
}

extern "C" void kernel_launch(void* const* d_in, const int* in_sizes, int n_in,
                              void* d_out, int out_size, void* d_ws, size_t ws_size,
                              hipStream_t stream) {
    const int*   weight = (const int*)d_in[0];
    const float* scale  = (const float*)d_in[1];
    const float* zp     = (const float*)d_in[2];
    const float* up     = (const float*)d_in[3];
    const float* down   = (const float*)d_in[4];
    float* out = (float*)d_out;

    __bf16* A_bf  = (__bf16*)d_ws;                  // 8192*128 bf16 = 2 MB
    __bf16* Bt_bf = A_bf + (size_t)O_DIM * RANK;    // 8192*128 bf16 = 2 MB

    k_convert_up<<<1024, 256, 0, stream>>>(up, A_bf);
    k_transpose_down<<<128, 256, 0, stream>>>(down, Bt_bf);

    dim3 grid(64, 64);   // x = column group (g), y = row tile
    k_main<<<grid, 256, 0, stream>>>(weight, scale, zp, A_bf, Bt_bf, out);
}